// Round 4
// baseline (15009.195 us; speedup 1.0000x reference)
//
#include <hip/hip_runtime.h>
#include <stdint.h>

// P_TNCN: seq=512, batch=128, states=512, out=256, inv_tau=0.5,
// alpha=0.01, beta=0.5.  float32 I/O.
//
// Per step (per batch row b, independent across b):
//   h_prior = 0.5*h + 0.5*(tanh(h) @ w_r^T + b_r)          [w_i term == 0]
//   x_pred  = tanh(h_prior) @ w_o^T + b_o
//   error   = x_pred - x_t                                   (output)
//   h_post  = h_prior - 0.01*sign(h_prior) - 0.5*(error @ w_f^T)
//
// R6: latency-pipelining round.  R5 (1024thr, +occupancy) regressed: barrier-
// correlated stalls don't shrink with more waves.  Back to R4's 512-thread
// structure + explicit rotating 3-buffer register prefetch (2 groups of 8
// uint4 ahead) in every matvec, and cross-phase pre-issue: each phase's first
// 2 weight groups are issued in the previous phase's tail (weight addresses
// are step-invariant).  Steady state keeps ~16 uint4 loads in flight, so the
// per-unroll-group L2 latency (~600cy loaded) hides under compute.
// Weights f16-packed (v_dot2_f32_f16), uint4 loads.  Workspace: 1 MB.

#define SEQ   512
#define BATCH 128
#define SD    512
#define OD    256

typedef _Float16 h2_t __attribute__((ext_vector_type(2)));

#if __has_builtin(__builtin_amdgcn_fdot2)
#define HAS_FDOT2 1
#else
#define HAS_FDOT2 0
#endif

__device__ __forceinline__ float tanh_fast(float x) {
    float e = __expf(2.0f * x);
    return 1.0f - 2.0f / (e + 1.0f);
}

__device__ __forceinline__ uint32_t pack_h2(float a, float b) {
    h2_t v;
    v.x = (_Float16)a;
    v.y = (_Float16)b;
    return __builtin_bit_cast(uint32_t, v);
}

__device__ __forceinline__ float dot2acc(uint32_t w, uint32_t a, float acc) {
#if HAS_FDOT2
    return __builtin_amdgcn_fdot2(__builtin_bit_cast(h2_t, a),
                                  __builtin_bit_cast(h2_t, w), acc, false);
#else
    h2_t av = __builtin_bit_cast(h2_t, a);
    h2_t wv = __builtin_bit_cast(h2_t, w);
    acc += (float)av.x * (float)wv.x;
    acc += (float)av.y * (float)wv.y;
    return acc;
#endif
}

__device__ __forceinline__ float dot8(uint4 w, uint4 a, float acc) {
    acc = dot2acc(w.x, a.x, acc);
    acc = dot2acc(w.y, a.y, acc);
    acc = dot2acc(w.z, a.z, acc);
    acc = dot2acc(w.w, a.w, acc);
    return acc;
}

// ---------------------------------------------------------------------------
// Pack kernel: transposed, 8-k-packed f16 weight images in workspace.
//   A4 uint4 [64][512] : A4[k8][s] = w_r[s][8k8..8k8+7]     (512 KB)
//   O4 uint4 [64][256] : O4[k8][o] = w_o[o][8k8..8k8+7]     (256 KB)  full k
//   F4 uint4 [32][512] : F4[o8][s] = w_f[s][8o8..8o8+7]     (256 KB)
// total 1 MB of workspace.
// ---------------------------------------------------------------------------
__global__ void pack_weights(const float* __restrict__ w_o,
                             const float* __restrict__ w_r,
                             const float* __restrict__ w_f,
                             uint4* __restrict__ ws)
{
    const int nA = 64 * 512;   // 32768 uint4
    const int nO = 64 * 256;   // 16384
    const int nF = 32 * 512;   // 16384
    int i = blockIdx.x * 256 + threadIdx.x;
    const float* p;
    if (i < nA) {
        int k8 = i >> 9, s = i & 511;
        p = &w_r[s * 512 + 8 * k8];
    } else if (i < nA + nO) {
        int j = i - nA;
        int k8 = j >> 8, o = j & 255;
        p = &w_o[o * 512 + 8 * k8];
    } else if (i < nA + nO + nF) {
        int j = i - nA - nO;
        int o8 = j >> 9, s = j & 511;
        p = &w_f[s * 256 + 8 * o8];
    } else {
        return;
    }
    ws[i] = make_uint4(pack_h2(p[0], p[1]), pack_h2(p[2], p[3]),
                       pack_h2(p[4], p[5]), pack_h2(p[6], p[7]));
}

// ---------------------------------------------------------------------------
// Main sequential scan: one block per batch row, h state in registers (s=tid).
// Rotating 3-buffer register pipeline; buffer index g%3 is compile-time
// (g-loops fully unrolled) so w[][] stays in VGPRs (rule: no runtime
// indexing of register arrays).
// Buffer schedule (verified no overlap):
//   A: g0..g7 use w[g%3]; pfA(g+2) issued while computing g.
//   After A-loop: pfB(0)->w0, pfB(1)->w1  (w0 free after A g6, w1 after g7).
//   B: g0..g3 use w[g%3]; pfB(g+2) while computing g.
//   After B-loop: pfC(0)->w0, pfC(1)->w1  (all free after B g3).
//   C: g0..g3 use w[g%3]; pfC(g+2) while computing g.
//   After C-loop: pfA(0)->w0, pfA(1)->w1 for next t (A addrs t-invariant).
// ---------------------------------------------------------------------------
__global__ __launch_bounds__(512)
void tncn_scan(const float* __restrict__ x,       // [512][128][256]
               const float* __restrict__ h_init,  // [128][512]
               const float* __restrict__ b_o,     // [256]
               const float* __restrict__ b_r,     // [512]
               const uint4* __restrict__ wsv,
               float* __restrict__ out)           // [512][128][256]
{
    const uint4* A4 = wsv;                  // [64][512]
    const uint4* O4 = wsv + 64 * 512;       // [64][256]
    const uint4* F4 = O4 + 64 * 256;        // [32][512]

    __shared__ __align__(16) _Float16 thA[512];  // tanh(h_post) prev step
    __shared__ __align__(16) _Float16 thB[512];  // tanh(h_prior) this step
    __shared__ __align__(16) _Float16 erh[256];  // error vector this step
    __shared__ float part[512];                  // partial sums for x_pred

    const int b   = blockIdx.x;
    const int tid = threadIdx.x;
    const int o   = tid & 255;
    const int kh  = tid >> 8;    // 0/1: k-half for phase B

    const float brf = b_r[tid];
    const float bof = (tid < 256) ? b_o[tid] : 0.0f;

    uint4 w[3][8];   // rotating weight prefetch buffers (96 VGPR)

    auto pfA = [&](int g) {
        #pragma unroll
        for (int j = 0; j < 8; ++j)
            w[g % 3][j] = A4[((g * 8 + j) << 9) + tid];
    };
    auto pfB = [&](int g) {
        #pragma unroll
        for (int j = 0; j < 8; ++j)
            w[g % 3][j] = O4[((kh * 32 + g * 8 + j) << 8) + o];
    };
    auto pfC = [&](int g) {
        #pragma unroll
        for (int j = 0; j < 8; ++j)
            w[g % 3][j] = F4[((g * 8 + j) << 9) + tid];
    };

    float hpost = h_init[b * SD + tid];
    thA[tid] = (_Float16)tanh_fast(hpost);

    // Warm the pipeline for the first phase A.
    pfA(0);
    pfA(1);
    __syncthreads();

    for (int t = 0; t < SEQ; ++t) {
        // Hoisted x_t load (consumed one matvec later; latency hidden).
        float xv = 0.0f;
        if (tid < 256) xv = x[(t * BATCH + b) * OD + tid];

        // ---- Phase A: h_prior[s=tid] = 0.5*h + 0.5*(tanh(h)@w_r^T + b_r)
        float acc = 0.0f;
        #pragma unroll
        for (int g = 0; g < 8; ++g) {
            if (g + 2 < 8) pfA(g + 2);
            #pragma unroll
            for (int j = 0; j < 8; ++j) {
                uint4 a = *(const uint4*)&thA[8 * (g * 8 + j)];
                acc = dot8(w[g % 3][j], a, acc);
            }
        }
        // Pre-issue phase B's first two groups (global-only; hides B cold start).
        pfB(0);
        pfB(1);
        float hp = 0.5f * hpost + 0.5f * (acc + brf);
        thB[tid] = (_Float16)tanh_fast(hp);
        __syncthreads();

        // ---- Phase B: x_pred[o] = tanh(h_prior)@w_o^T + b_o ; err = xp - x
        float accB = 0.0f;
        #pragma unroll
        for (int g = 0; g < 4; ++g) {
            if (g + 2 < 4) pfB(g + 2);
            #pragma unroll
            for (int j = 0; j < 8; ++j) {
                uint4 a = *(const uint4*)&thB[8 * (kh * 32 + g * 8 + j)];
                accB = dot8(w[g % 3][j], a, accB);
            }
        }
        part[tid] = accB;
        // Pre-issue phase C's first two groups.
        pfC(0);
        pfC(1);
        __syncthreads();
        if (tid < 256) {
            float xp = part[tid] + part[tid + 256] + bof;
            float e  = xp - xv;
            erh[tid] = (_Float16)e;
            out[(t * BATCH + b) * OD + tid] = e;
        }
        __syncthreads();

        // ---- Phase C: h_post[s] = h_prior - 0.01*sign(h_prior) - 0.5*(er@w_f^T)
        float accC = 0.0f;
        #pragma unroll
        for (int g = 0; g < 4; ++g) {
            if (g + 2 < 4) pfC(g + 2);
            #pragma unroll
            for (int j = 0; j < 8; ++j) {
                uint4 e = *(const uint4*)&erh[8 * (g * 8 + j)];
                accC = dot8(w[g % 3][j], e, accC);
            }
        }
        // Pre-issue next step's phase A groups (A addresses are t-invariant).
        pfA(0);
        pfA(1);
        float sg = (hp > 0.0f) ? 1.0f : ((hp < 0.0f) ? -1.0f : 0.0f);
        hpost = hp - 0.01f * sg - 0.5f * accC;
        thA[tid] = (_Float16)tanh_fast(hpost);
        __syncthreads();
    }
}

extern "C" void kernel_launch(void* const* d_in, const int* in_sizes, int n_in,
                              void* d_out, int out_size, void* d_ws, size_t ws_size,
                              hipStream_t stream)
{
    // setup_inputs order: x, h_init, w_o, b_o, w_r, b_r, w_f, w_i
    const float* x  = (const float*)d_in[0];
    const float* h0 = (const float*)d_in[1];
    const float* wo = (const float*)d_in[2];
    const float* bo = (const float*)d_in[3];
    const float* wr = (const float*)d_in[4];
    const float* br = (const float*)d_in[5];
    const float* wf = (const float*)d_in[6];
    // d_in[7] (w_i) multiplies a zeros tensor in the reference — unused.

    uint4* ws = (uint4*)d_ws;
    float* out = (float*)d_out;

    const int total_pack = 64 * 512 + 64 * 256 + 32 * 512;  // 65536 uint4
    pack_weights<<<(total_pack + 255) / 256, 256, 0, stream>>>(wo, wr, wf, ws);
    tncn_scan<<<BATCH, 512, 0, stream>>>(x, h0, bo, br, ws, out);
}

// Round 6
// 5767.817 us; speedup vs baseline: 2.6022x; 2.6022x over previous
//
#include <hip/hip_runtime.h>
#include <stdint.h>

// P_TNCN: seq=512, batch=128, states=512, out=256, inv_tau=0.5,
// alpha=0.01, beta=0.5.  float32 I/O.
//
// Per step (per batch row b, independent across b):
//   h_prior = 0.5*h + 0.5*(tanh(h) @ w_r^T + b_r)          [w_i term == 0]
//   x_pred  = tanh(h_prior) @ w_o^T + b_o
//   error   = x_pred - x_t                                   (output)
//   h_post  = h_prior - 0.01*sign(h_prior) - 0.5*(error @ w_f^T)
//
// R8 = R7 resubmit (R7 bench died in container infra twice, no counters; same
// signature as R3's transient failure whose resubmit ran clean).  Structure:
// R4's compiler-scheduled sequential loads + G=2 batch rows per block.  Each
// weight quad is loaded once and dotted against TWO activation vectors ->
// per row-step: weight loads halved (128->64), L2 weight traffic halved
// (15.6 -> 7.8 TB/s), 2x compute per load to hide latency.  64 blocks x 512
// threads.  Weights f16-packed (v_dot2_f32_f16), uint4 loads.  Workspace: 1 MB.

#define SEQ   512
#define BATCH 128
#define SD    512
#define OD    256

typedef _Float16 h2_t __attribute__((ext_vector_type(2)));

#if __has_builtin(__builtin_amdgcn_fdot2)
#define HAS_FDOT2 1
#else
#define HAS_FDOT2 0
#endif

__device__ __forceinline__ float tanh_fast(float x) {
    float e = __expf(2.0f * x);
    return 1.0f - 2.0f / (e + 1.0f);
}

__device__ __forceinline__ uint32_t pack_h2(float a, float b) {
    h2_t v;
    v.x = (_Float16)a;
    v.y = (_Float16)b;
    return __builtin_bit_cast(uint32_t, v);
}

__device__ __forceinline__ float dot2acc(uint32_t w, uint32_t a, float acc) {
#if HAS_FDOT2
    return __builtin_amdgcn_fdot2(__builtin_bit_cast(h2_t, a),
                                  __builtin_bit_cast(h2_t, w), acc, false);
#else
    h2_t av = __builtin_bit_cast(h2_t, a);
    h2_t wv = __builtin_bit_cast(h2_t, w);
    acc += (float)av.x * (float)wv.x;
    acc += (float)av.y * (float)wv.y;
    return acc;
#endif
}

__device__ __forceinline__ float dot8(uint4 w, uint4 a, float acc) {
    acc = dot2acc(w.x, a.x, acc);
    acc = dot2acc(w.y, a.y, acc);
    acc = dot2acc(w.z, a.z, acc);
    acc = dot2acc(w.w, a.w, acc);
    return acc;
}

// ---------------------------------------------------------------------------
// Pack kernel: transposed, 8-k-packed f16 weight images in workspace.
//   A4 uint4 [64][512] : A4[k8][s] = w_r[s][8k8..8k8+7]     (512 KB)
//   O4 uint4 [64][256] : O4[k8][o] = w_o[o][8k8..8k8+7]     (256 KB)  full k
//   F4 uint4 [32][512] : F4[o8][s] = w_f[s][8o8..8o8+7]     (256 KB)
// total 1 MB of workspace.
// ---------------------------------------------------------------------------
__global__ void pack_weights(const float* __restrict__ w_o,
                             const float* __restrict__ w_r,
                             const float* __restrict__ w_f,
                             uint4* __restrict__ ws)
{
    const int nA = 64 * 512;   // 32768 uint4
    const int nO = 64 * 256;   // 16384
    const int nF = 32 * 512;   // 16384
    int i = blockIdx.x * 256 + threadIdx.x;
    const float* p;
    if (i < nA) {
        int k8 = i >> 9, s = i & 511;
        p = &w_r[s * 512 + 8 * k8];
    } else if (i < nA + nO) {
        int j = i - nA;
        int k8 = j >> 8, o = j & 255;
        p = &w_o[o * 512 + 8 * k8];
    } else if (i < nA + nO + nF) {
        int j = i - nA - nO;
        int o8 = j >> 9, s = j & 511;
        p = &w_f[s * 256 + 8 * o8];
    } else {
        return;
    }
    ws[i] = make_uint4(pack_h2(p[0], p[1]), pack_h2(p[2], p[3]),
                       pack_h2(p[4], p[5]), pack_h2(p[6], p[7]));
}

// ---------------------------------------------------------------------------
// Main sequential scan: one block per PAIR of batch rows, h state for both
// rows in registers (s=tid).  Every weight quad load feeds two dot8's.
// ---------------------------------------------------------------------------
__global__ __launch_bounds__(512)
void tncn_scan(const float* __restrict__ x,       // [512][128][256]
               const float* __restrict__ h_init,  // [128][512]
               const float* __restrict__ b_o,     // [256]
               const float* __restrict__ b_r,     // [512]
               const uint4* __restrict__ wsv,
               float* __restrict__ out)           // [512][128][256]
{
    const uint4* A4 = wsv;                  // [64][512]
    const uint4* O4 = wsv + 64 * 512;       // [64][256]
    const uint4* F4 = O4 + 64 * 256;        // [32][512]

    __shared__ __align__(16) _Float16 thA0[512], thA1[512];  // tanh(h_post)
    __shared__ __align__(16) _Float16 thB0[512], thB1[512];  // tanh(h_prior)
    __shared__ __align__(16) _Float16 erh0[256], erh1[256];  // errors
    __shared__ float part0[512], part1[512];                 // x_pred partials

    const int b0  = 2 * blockIdx.x;
    const int b1  = b0 + 1;
    const int tid = threadIdx.x;
    const int o   = tid & 255;
    const int kh  = tid >> 8;    // 0/1: k-half for phase B

    const float brf = b_r[tid];
    const float bof = (tid < 256) ? b_o[tid] : 0.0f;

    float hpost0 = h_init[b0 * SD + tid];
    float hpost1 = h_init[b1 * SD + tid];
    thA0[tid] = (_Float16)tanh_fast(hpost0);
    thA1[tid] = (_Float16)tanh_fast(hpost1);
    __syncthreads();

    for (int t = 0; t < SEQ; ++t) {
        // Hoisted x_t loads (consumed one matvec later; latency hidden).
        float xv0 = 0.0f, xv1 = 0.0f;
        if (tid < 256) {
            xv0 = x[(t * BATCH + b0) * OD + tid];
            xv1 = x[(t * BATCH + b1) * OD + tid];
        }

        // ---- Phase A: h_prior = 0.5*h + 0.5*(tanh(h)@w_r^T + b_r)
        float acc0 = 0.0f, acc1 = 0.0f;
        #pragma unroll 8
        for (int k8 = 0; k8 < 64; ++k8) {
            uint4 u  = A4[(k8 << 9) + tid];
            uint4 a0 = *(const uint4*)&thA0[8 * k8];
            uint4 a1 = *(const uint4*)&thA1[8 * k8];
            acc0 = dot8(u, a0, acc0);
            acc1 = dot8(u, a1, acc1);
        }
        float hp0 = 0.5f * hpost0 + 0.5f * (acc0 + brf);
        float hp1 = 0.5f * hpost1 + 0.5f * (acc1 + brf);
        thB0[tid] = (_Float16)tanh_fast(hp0);
        thB1[tid] = (_Float16)tanh_fast(hp1);
        __syncthreads();

        // ---- Phase B: x_pred = tanh(h_prior)@w_o^T + b_o ; err = xp - x
        float accB0 = 0.0f, accB1 = 0.0f;
        {
            const int k80 = kh * 32;
            #pragma unroll 8
            for (int k8i = 0; k8i < 32; ++k8i) {
                const int k8 = k80 + k8i;
                uint4 u  = O4[(k8 << 8) + o];
                uint4 a0 = *(const uint4*)&thB0[8 * k8];
                uint4 a1 = *(const uint4*)&thB1[8 * k8];
                accB0 = dot8(u, a0, accB0);
                accB1 = dot8(u, a1, accB1);
            }
        }
        part0[tid] = accB0;
        part1[tid] = accB1;
        __syncthreads();
        if (tid < 256) {
            float xp0 = part0[tid] + part0[tid + 256] + bof;
            float xp1 = part1[tid] + part1[tid + 256] + bof;
            float e0  = xp0 - xv0;
            float e1  = xp1 - xv1;
            erh0[tid] = (_Float16)e0;
            erh1[tid] = (_Float16)e1;
            out[(t * BATCH + b0) * OD + tid] = e0;
            out[(t * BATCH + b1) * OD + tid] = e1;
        }
        __syncthreads();

        // ---- Phase C: h_post = h_prior - 0.01*sign(h_prior) - 0.5*(er@w_f^T)
        float accC0 = 0.0f, accC1 = 0.0f;
        #pragma unroll 8
        for (int o8 = 0; o8 < 32; ++o8) {
            uint4 u  = F4[(o8 << 9) + tid];
            uint4 e0 = *(const uint4*)&erh0[8 * o8];
            uint4 e1 = *(const uint4*)&erh1[8 * o8];
            accC0 = dot8(u, e0, accC0);
            accC1 = dot8(u, e1, accC1);
        }
        float sg0 = (hp0 > 0.0f) ? 1.0f : ((hp0 < 0.0f) ? -1.0f : 0.0f);
        float sg1 = (hp1 > 0.0f) ? 1.0f : ((hp1 < 0.0f) ? -1.0f : 0.0f);
        hpost0 = hp0 - 0.01f * sg0 - 0.5f * accC0;
        hpost1 = hp1 - 0.01f * sg1 - 0.5f * accC1;
        thA0[tid] = (_Float16)tanh_fast(hpost0);
        thA1[tid] = (_Float16)tanh_fast(hpost1);
        __syncthreads();
    }
}

extern "C" void kernel_launch(void* const* d_in, const int* in_sizes, int n_in,
                              void* d_out, int out_size, void* d_ws, size_t ws_size,
                              hipStream_t stream)
{
    // setup_inputs order: x, h_init, w_o, b_o, w_r, b_r, w_f, w_i
    const float* x  = (const float*)d_in[0];
    const float* h0 = (const float*)d_in[1];
    const float* wo = (const float*)d_in[2];
    const float* bo = (const float*)d_in[3];
    const float* wr = (const float*)d_in[4];
    const float* br = (const float*)d_in[5];
    const float* wf = (const float*)d_in[6];
    // d_in[7] (w_i) multiplies a zeros tensor in the reference — unused.

    uint4* ws = (uint4*)d_ws;
    float* out = (float*)d_out;

    const int total_pack = 64 * 512 + 64 * 256 + 32 * 512;  // 65536 uint4
    pack_weights<<<(total_pack + 255) / 256, 256, 0, stream>>>(wo, wr, wf, ws);
    tncn_scan<<<BATCH / 2, 512, 0, stream>>>(x, h0, bo, br, ws, out);
}

// Round 7
// 3960.128 us; speedup vs baseline: 3.7901x; 1.4565x over previous
//
#include <hip/hip_runtime.h>
#include <stdint.h>

// P_TNCN: seq=512, batch=128, states=512, out=256, inv_tau=0.5,
// alpha=0.01, beta=0.5.  float32 I/O.
//
// Per step (per batch row b, independent across b):
//   h_prior = 0.5*h + 0.5*(tanh(h) @ w_r^T + b_r)          [w_i term == 0]
//   x_pred  = tanh(h_prior) @ w_o^T + b_o
//   error   = x_pred - x_t                                   (output)
//   h_post  = h_prior - 0.01*sign(h_prior) - 0.5*(error @ w_f^T)
//
// R9: per-CU L2-BW round.  Model established by R4/R8 counters: each block
// streams the full 1 MB weight image from L2 every step and a CU pulls only
// ~53-64 B/cy from L2 -> R4 (4237us) sat at ~94% of that per-CU floor; G>1
// provably cannot beat it (same bytes/step/CU, fewer CUs).  This round keeps
// R4's exact structure (128 blocks x 512 thr, bitwise-same accumulation
// order) and stages the first NSTAGE rows of A4 in LDS once before the
// t-loop: staged bytes move to the ds_read pipe, shrinking the per-step L2
// stream 1024 -> 880 KB (NSTAGE=18, 144 KB dyn LDS via hipFuncSetAttribute;
// fallback NSTAGE=7 / 56 KB if the attribute is unsupported).
// Weights f16-packed (v_dot2_f32_f16), uint4 loads.  Workspace: 1 MB.

#define SEQ   512
#define BATCH 128
#define SD    512
#define OD    256

typedef _Float16 h2_t __attribute__((ext_vector_type(2)));

#if __has_builtin(__builtin_amdgcn_fdot2)
#define HAS_FDOT2 1
#else
#define HAS_FDOT2 0
#endif

__device__ __forceinline__ float tanh_fast(float x) {
    float e = __expf(2.0f * x);
    return 1.0f - 2.0f / (e + 1.0f);
}

__device__ __forceinline__ uint32_t pack_h2(float a, float b) {
    h2_t v;
    v.x = (_Float16)a;
    v.y = (_Float16)b;
    return __builtin_bit_cast(uint32_t, v);
}

__device__ __forceinline__ float dot2acc(uint32_t w, uint32_t a, float acc) {
#if HAS_FDOT2
    return __builtin_amdgcn_fdot2(__builtin_bit_cast(h2_t, a),
                                  __builtin_bit_cast(h2_t, w), acc, false);
#else
    h2_t av = __builtin_bit_cast(h2_t, a);
    h2_t wv = __builtin_bit_cast(h2_t, w);
    acc += (float)av.x * (float)wv.x;
    acc += (float)av.y * (float)wv.y;
    return acc;
#endif
}

__device__ __forceinline__ float dot8(uint4 w, uint4 a, float acc) {
    acc = dot2acc(w.x, a.x, acc);
    acc = dot2acc(w.y, a.y, acc);
    acc = dot2acc(w.z, a.z, acc);
    acc = dot2acc(w.w, a.w, acc);
    return acc;
}

// ---------------------------------------------------------------------------
// Pack kernel: transposed, 8-k-packed f16 weight images in workspace.
//   A4 uint4 [64][512] : A4[k8][s] = w_r[s][8k8..8k8+7]     (512 KB)
//   O4 uint4 [64][256] : O4[k8][o] = w_o[o][8k8..8k8+7]     (256 KB)  full k
//   F4 uint4 [32][512] : F4[o8][s] = w_f[s][8o8..8o8+7]     (256 KB)
// total 1 MB of workspace.
// ---------------------------------------------------------------------------
__global__ void pack_weights(const float* __restrict__ w_o,
                             const float* __restrict__ w_r,
                             const float* __restrict__ w_f,
                             uint4* __restrict__ ws)
{
    const int nA = 64 * 512;   // 32768 uint4
    const int nO = 64 * 256;   // 16384
    const int nF = 32 * 512;   // 16384
    int i = blockIdx.x * 256 + threadIdx.x;
    const float* p;
    if (i < nA) {
        int k8 = i >> 9, s = i & 511;
        p = &w_r[s * 512 + 8 * k8];
    } else if (i < nA + nO) {
        int j = i - nA;
        int k8 = j >> 8, o = j & 255;
        p = &w_o[o * 512 + 8 * k8];
    } else if (i < nA + nO + nF) {
        int j = i - nA - nO;
        int o8 = j >> 9, s = j & 511;
        p = &w_f[s * 256 + 8 * o8];
    } else {
        return;
    }
    ws[i] = make_uint4(pack_h2(p[0], p[1]), pack_h2(p[2], p[3]),
                       pack_h2(p[4], p[5]), pack_h2(p[6], p[7]));
}

// ---------------------------------------------------------------------------
// Main sequential scan: one block per batch row, h state in registers (s=tid).
// First NSTAGE rows of A4 live in LDS (loaded once); the rest stream from L2.
// Accumulation order identical to R4 (k8 ascending) -> bitwise-same result.
// ---------------------------------------------------------------------------
template <int NSTAGE>
__global__ __launch_bounds__(512)
void tncn_scan(const float* __restrict__ x,       // [512][128][256]
               const float* __restrict__ h_init,  // [128][512]
               const float* __restrict__ b_o,     // [256]
               const float* __restrict__ b_r,     // [512]
               const uint4* __restrict__ wsv,
               float* __restrict__ out)           // [512][128][256]
{
    const uint4* A4 = wsv;                  // [64][512]
    const uint4* O4 = wsv + 64 * 512;       // [64][256]
    const uint4* F4 = O4 + 64 * 256;        // [32][512]

    extern __shared__ __align__(16) char smem_raw[];
    uint4* sA = (uint4*)smem_raw;                // [NSTAGE*512] staged A4

    __shared__ __align__(16) _Float16 thA[512];  // tanh(h_post) prev step
    __shared__ __align__(16) _Float16 thB[512];  // tanh(h_prior) this step
    __shared__ __align__(16) _Float16 erh[256];  // error vector this step
    __shared__ float part[512];                  // partial sums for x_pred

    const int b   = blockIdx.x;
    const int tid = threadIdx.x;
    const int o   = tid & 255;
    const int kh  = tid >> 8;    // 0/1: k-half for phase B

    const float brf = b_r[tid];
    const float bof = (tid < 256) ? b_o[tid] : 0.0f;

    // Stage A4 rows [0, NSTAGE) into LDS once (coalesced, ~3k cy).
    #pragma unroll
    for (int r = 0; r < NSTAGE; ++r)
        sA[r * 512 + tid] = A4[r * 512 + tid];

    float hpost = h_init[b * SD + tid];
    thA[tid] = (_Float16)tanh_fast(hpost);
    __syncthreads();

    for (int t = 0; t < SEQ; ++t) {
        // Hoisted x_t load (consumed one matvec later; latency hidden).
        float xv = 0.0f;
        if (tid < 256) xv = x[(t * BATCH + b) * OD + tid];

        // ---- Phase A: h_prior[s=tid] = 0.5*h + 0.5*(tanh(h)@w_r^T + b_r)
        float acc = 0.0f;
        // k8 in [0, NSTAGE): weights from LDS (off the L2 stream).
        #pragma unroll
        for (int k8 = 0; k8 < NSTAGE; ++k8) {
            uint4 u = sA[(k8 << 9) + tid];
            uint4 a = *(const uint4*)&thA[8 * k8];
            acc = dot8(u, a, acc);
        }
        // k8 in [NSTAGE, 64): weights stream from L2.
        #pragma unroll 8
        for (int k8 = NSTAGE; k8 < 64; ++k8) {
            uint4 u = A4[(k8 << 9) + tid];
            uint4 a = *(const uint4*)&thA[8 * k8];
            acc = dot8(u, a, acc);
        }
        float hp = 0.5f * hpost + 0.5f * (acc + brf);
        thB[tid] = (_Float16)tanh_fast(hp);
        __syncthreads();

        // ---- Phase B: x_pred[o] = tanh(h_prior)@w_o^T + b_o ; err = xp - x
        float accB = 0.0f;
        {
            const int k80 = kh * 32;
            #pragma unroll 8
            for (int k8i = 0; k8i < 32; ++k8i) {
                const int k8 = k80 + k8i;
                uint4 u = O4[(k8 << 8) + o];
                uint4 a = *(const uint4*)&thB[8 * k8];
                accB = dot8(u, a, accB);
            }
        }
        part[tid] = accB;
        __syncthreads();
        if (tid < 256) {
            float xp = part[tid] + part[tid + 256] + bof;
            float e  = xp - xv;
            erh[tid] = (_Float16)e;
            out[(t * BATCH + b) * OD + tid] = e;
        }
        __syncthreads();

        // ---- Phase C: h_post[s] = h_prior - 0.01*sign(h_prior) - 0.5*(er@w_f^T)
        float accC = 0.0f;
        #pragma unroll 8
        for (int o8 = 0; o8 < 32; ++o8) {
            uint4 u = F4[(o8 << 9) + tid];
            uint4 e = *(const uint4*)&erh[8 * o8];
            accC = dot8(u, e, accC);
        }
        float sg = (hp > 0.0f) ? 1.0f : ((hp < 0.0f) ? -1.0f : 0.0f);
        hpost = hp - 0.01f * sg - 0.5f * accC;
        thA[tid] = (_Float16)tanh_fast(hpost);
        __syncthreads();
    }
}

extern "C" void kernel_launch(void* const* d_in, const int* in_sizes, int n_in,
                              void* d_out, int out_size, void* d_ws, size_t ws_size,
                              hipStream_t stream)
{
    // setup_inputs order: x, h_init, w_o, b_o, w_r, b_r, w_f, w_i
    const float* x  = (const float*)d_in[0];
    const float* h0 = (const float*)d_in[1];
    const float* wo = (const float*)d_in[2];
    const float* bo = (const float*)d_in[3];
    const float* wr = (const float*)d_in[4];
    const float* br = (const float*)d_in[5];
    const float* wf = (const float*)d_in[6];
    // d_in[7] (w_i) multiplies a zeros tensor in the reference — unused.

    uint4* ws = (uint4*)d_ws;
    float* out = (float*)d_out;

    const int total_pack = 64 * 512 + 64 * 256 + 32 * 512;  // 65536 uint4
    pack_weights<<<(total_pack + 255) / 256, 256, 0, stream>>>(wo, wr, wf, ws);

    // Big variant: 18 rows staged = 147456 B dynamic LDS (needs opt-in).
    // Fallback: 7 rows = 57344 B (within default 64 KB limit).
    static int nstage_sel = -1;
    if (nstage_sel < 0) {
        hipError_t e = hipFuncSetAttribute(
            (const void*)tncn_scan<18>,
            hipFuncAttributeMaxDynamicSharedMemorySize, 18 * 512 * 16);
        nstage_sel = (e == hipSuccess) ? 18 : 7;
    }
    if (nstage_sel == 18) {
        tncn_scan<18><<<BATCH, 512, 18 * 512 * 16, stream>>>(x, h0, bo, br, ws, out);
    } else {
        tncn_scan<7><<<BATCH, 512, 7 * 512 * 16, stream>>>(x, h0, bo, br, ws, out);
    }
}

// Round 8
// 3653.692 us; speedup vs baseline: 4.1080x; 1.0839x over previous
//
#include <hip/hip_runtime.h>
#include <stdint.h>

// P_TNCN: seq=512, batch=128, states=512, out=256, inv_tau=0.5,
// alpha=0.01, beta=0.5.  float32 I/O.
//
// Per step (per batch row b, independent across b):
//   h_prior = 0.5*h + 0.5*(tanh(h) @ w_r^T + b_r)          [w_i term == 0]
//   x_pred  = tanh(h_prior) @ w_o^T + b_o
//   error   = x_pred - x_t                                   (output)
//   h_post  = h_prior - 0.01*sign(h_prior) - 0.5*(error @ w_f^T)
//
// R10: byte-diet round.  Model (calibrated on R4/R9 counters): step cycles =
// 11.5 cy/KB of per-CU L2 weight stream + 8050 cy fixed.  Only shrinking the
// stream helps.  This round: w_r and w_o stored as fp8-e5m2 = top byte of
// f16 (RTNE); decode = byte<<8 via one v_perm_b32 per f16-pair, then the
// existing v_dot2_f32_f16 path (no scale factor needed - e5m2 keeps the f16
// exponent).  w_f stays f16 (it multiplies the O(1) error activations - the
// sensitive path).  Stream: 1024 -> 584 KB/step (A8 256KB - 56KB LDS-staged,
// O8 128KB, F4 256KB).  Numerics: e5m2 RMS rel err ~3.6% on weights whose
// matvec outputs are O(0.002..0.06) vs O(1) output scale -> absmax impact
// ~2e-4, negligible.  Structure otherwise identical to R9 (128 blk x 512 thr,
// 7-row LDS stage = 57344B dynamic, proven size).  Workspace: 640 KB.

#define SEQ   512
#define BATCH 128
#define SD    512
#define OD    256
#define NST   7     // A8 rows staged in LDS (7*512*16B = 57344 B)

typedef _Float16 h2_t __attribute__((ext_vector_type(2)));

#if __has_builtin(__builtin_amdgcn_fdot2)
#define HAS_FDOT2 1
#else
#define HAS_FDOT2 0
#endif

#if __has_builtin(__builtin_amdgcn_perm)
#define HAS_PERM 1
#else
#define HAS_PERM 0
#endif

__device__ __forceinline__ float tanh_fast(float x) {
    float e = __expf(2.0f * x);
    return 1.0f - 2.0f / (e + 1.0f);
}

__device__ __forceinline__ uint32_t pack_h2(float a, float b) {
    h2_t v;
    v.x = (_Float16)a;
    v.y = (_Float16)b;
    return __builtin_bit_cast(uint32_t, v);
}

// f32 -> fp8 e5m2 byte (= f16 RTNE, then RTNE-truncate to top byte).
// Weights are tiny (|w| << 1): no overflow; carry into exponent is correct IEEE.
__device__ __forceinline__ uint32_t f32_to_fp8(float f) {
    _Float16 h = (_Float16)f;
    uint32_t u = (uint32_t)__builtin_bit_cast(uint16_t, h);
    return ((u + 0x7Fu + ((u >> 8) & 1u)) >> 8) & 0xFFu;
}

// Decode: 4 packed e5m2 bytes -> two f16-pair uints.  byte<<8 is the f16.
__device__ __forceinline__ uint32_t dec_lo(uint32_t b4) {
#if HAS_PERM
    return __builtin_amdgcn_perm(b4, 0u, 0x05000400u); // [0,b0,0,b1]
#else
    return ((b4 & 0xFFu) << 8) | ((b4 & 0xFF00u) << 16);
#endif
}
__device__ __forceinline__ uint32_t dec_hi(uint32_t b4) {
#if HAS_PERM
    return __builtin_amdgcn_perm(b4, 0u, 0x07000600u); // [0,b2,0,b3]
#else
    return ((b4 & 0x00FF0000u) >> 8) | (b4 & 0xFF000000u);
#endif
}

__device__ __forceinline__ float dot2acc(uint32_t w, uint32_t a, float acc) {
#if HAS_FDOT2
    return __builtin_amdgcn_fdot2(__builtin_bit_cast(h2_t, a),
                                  __builtin_bit_cast(h2_t, w), acc, false);
#else
    h2_t av = __builtin_bit_cast(h2_t, a);
    h2_t wv = __builtin_bit_cast(h2_t, w);
    acc += (float)av.x * (float)wv.x;
    acc += (float)av.y * (float)wv.y;
    return acc;
#endif
}

// f16 path: uint4 = 8 f16 weights vs 8 f16 acts.
__device__ __forceinline__ float dot8(uint4 w, uint4 a, float acc) {
    acc = dot2acc(w.x, a.x, acc);
    acc = dot2acc(w.y, a.y, acc);
    acc = dot2acc(w.z, a.z, acc);
    acc = dot2acc(w.w, a.w, acc);
    return acc;
}

// fp8 path: uint4 = 16 e5m2 weights vs 16 f16 acts (two uint4).
__device__ __forceinline__ float dot16q(uint4 wq, uint4 a0, uint4 a1, float acc) {
    acc = dot2acc(dec_lo(wq.x), a0.x, acc);
    acc = dot2acc(dec_hi(wq.x), a0.y, acc);
    acc = dot2acc(dec_lo(wq.y), a0.z, acc);
    acc = dot2acc(dec_hi(wq.y), a0.w, acc);
    acc = dot2acc(dec_lo(wq.z), a1.x, acc);
    acc = dot2acc(dec_hi(wq.z), a1.y, acc);
    acc = dot2acc(dec_lo(wq.w), a1.z, acc);
    acc = dot2acc(dec_hi(wq.w), a1.w, acc);
    return acc;
}

// ---------------------------------------------------------------------------
// Pack kernel: workspace images (uint4 units):
//   A8 [32][512] : A8[k16][s] = fp8 w_r[s][16k16..16k16+15]   (256 KB)
//   O8 [32][256] : O8[k16][o] = fp8 w_o[o][16k16..16k16+15]   (128 KB)
//   F4 [32][512] : F4[o8][s]  = f16 w_f[s][8o8..8o8+7]        (256 KB)
// total 640 KB of workspace.
// ---------------------------------------------------------------------------
__global__ void pack_weights(const float* __restrict__ w_o,
                             const float* __restrict__ w_r,
                             const float* __restrict__ w_f,
                             uint4* __restrict__ ws)
{
    const int nA = 32 * 512;   // 16384 uint4
    const int nO = 32 * 256;   //  8192
    const int nF = 32 * 512;   // 16384
    int i = blockIdx.x * 256 + threadIdx.x;
    if (i < nA + nO) {
        const float* p;
        if (i < nA) {
            int k16 = i >> 9, s = i & 511;
            p = &w_r[s * 512 + 16 * k16];
        } else {
            int j = i - nA;
            int k16 = j >> 8, o = j & 255;
            p = &w_o[o * 512 + 16 * k16];
        }
        uint32_t q[4];
        #pragma unroll
        for (int g = 0; g < 4; ++g)
            q[g] = f32_to_fp8(p[4 * g + 0])
                 | (f32_to_fp8(p[4 * g + 1]) << 8)
                 | (f32_to_fp8(p[4 * g + 2]) << 16)
                 | (f32_to_fp8(p[4 * g + 3]) << 24);
        ws[i] = make_uint4(q[0], q[1], q[2], q[3]);
    } else if (i < nA + nO + nF) {
        int j = i - nA - nO;
        int o8 = j >> 9, s = j & 511;
        const float* p = &w_f[s * 256 + 8 * o8];
        ws[i] = make_uint4(pack_h2(p[0], p[1]), pack_h2(p[2], p[3]),
                           pack_h2(p[4], p[5]), pack_h2(p[6], p[7]));
    }
}

// ---------------------------------------------------------------------------
// Main sequential scan: one block per batch row, h state in registers (s=tid).
// A8 rows [0,NST) live in LDS (loaded once); accumulation order = ascending k
// everywhere (same summation sequence as R9; only weight rounding changed).
// ---------------------------------------------------------------------------
__global__ __launch_bounds__(512)
void tncn_scan(const float* __restrict__ x,       // [512][128][256]
               const float* __restrict__ h_init,  // [128][512]
               const float* __restrict__ b_o,     // [256]
               const float* __restrict__ b_r,     // [512]
               const uint4* __restrict__ wsv,
               float* __restrict__ out)           // [512][128][256]
{
    const uint4* A8 = wsv;                       // [32][512]
    const uint4* O8 = wsv + 32 * 512;            // [32][256]
    const uint4* F4 = wsv + 32 * 512 + 32 * 256; // [32][512]

    extern __shared__ __align__(16) char smem_raw[];
    uint4* sA = (uint4*)smem_raw;                // [NST*512] staged A8 rows

    __shared__ __align__(16) _Float16 thA[512];  // tanh(h_post) prev step
    __shared__ __align__(16) _Float16 thB[512];  // tanh(h_prior) this step
    __shared__ __align__(16) _Float16 erh[256];  // error vector this step
    __shared__ float part[512];                  // partial sums for x_pred

    const int b   = blockIdx.x;
    const int tid = threadIdx.x;
    const int o   = tid & 255;
    const int kh  = tid >> 8;    // 0/1: k-half for phase B

    const float brf = b_r[tid];
    const float bof = (tid < 256) ? b_o[tid] : 0.0f;

    // Stage A8 rows [0, NST) into LDS once (coalesced).
    #pragma unroll
    for (int r = 0; r < NST; ++r)
        sA[r * 512 + tid] = A8[r * 512 + tid];

    float hpost = h_init[b * SD + tid];
    thA[tid] = (_Float16)tanh_fast(hpost);
    __syncthreads();

    for (int t = 0; t < SEQ; ++t) {
        // Hoisted x_t load (consumed one matvec later; latency hidden).
        float xv = 0.0f;
        if (tid < 256) xv = x[(t * BATCH + b) * OD + tid];

        // ---- Phase A: h_prior[s=tid] = 0.5*h + 0.5*(tanh(h)@w_r^T + b_r)
        float acc = 0.0f;
        // k16 in [0, NST): weights from LDS (off the L2 stream).
        #pragma unroll
        for (int k16 = 0; k16 < NST; ++k16) {
            uint4 wq = sA[(k16 << 9) + tid];
            uint4 a0 = *(const uint4*)&thA[16 * k16];
            uint4 a1 = *(const uint4*)&thA[16 * k16 + 8];
            acc = dot16q(wq, a0, a1, acc);
        }
        // k16 in [NST, 32): weights stream from L2.
        #pragma unroll 5
        for (int k16 = NST; k16 < 32; ++k16) {
            uint4 wq = A8[(k16 << 9) + tid];
            uint4 a0 = *(const uint4*)&thA[16 * k16];
            uint4 a1 = *(const uint4*)&thA[16 * k16 + 8];
            acc = dot16q(wq, a0, a1, acc);
        }
        float hp = 0.5f * hpost + 0.5f * (acc + brf);
        thB[tid] = (_Float16)tanh_fast(hp);
        __syncthreads();

        // ---- Phase B: x_pred[o] = tanh(h_prior)@w_o^T + b_o ; err = xp - x
        float accB = 0.0f;
        {
            const int k160 = kh * 16;
            #pragma unroll 8
            for (int k16i = 0; k16i < 16; ++k16i) {
                const int k16 = k160 + k16i;
                uint4 wq = O8[(k16 << 8) + o];
                uint4 a0 = *(const uint4*)&thB[16 * k16];
                uint4 a1 = *(const uint4*)&thB[16 * k16 + 8];
                accB = dot16q(wq, a0, a1, accB);
            }
        }
        part[tid] = accB;
        __syncthreads();
        if (tid < 256) {
            float xp = part[tid] + part[tid + 256] + bof;
            float e  = xp - xv;
            erh[tid] = (_Float16)e;
            out[(t * BATCH + b) * OD + tid] = e;
        }
        __syncthreads();

        // ---- Phase C: h_post[s] = h_prior - 0.01*sign(h_prior) - 0.5*(er@w_f^T)
        float accC = 0.0f;
        #pragma unroll 8
        for (int o8 = 0; o8 < 32; ++o8) {
            uint4 u = F4[(o8 << 9) + tid];
            uint4 e = *(const uint4*)&erh[8 * o8];
            accC = dot8(u, e, accC);
        }
        float sg = (hp > 0.0f) ? 1.0f : ((hp < 0.0f) ? -1.0f : 0.0f);
        hpost = hp - 0.01f * sg - 0.5f * accC;
        thA[tid] = (_Float16)tanh_fast(hpost);
        __syncthreads();
    }
}

extern "C" void kernel_launch(void* const* d_in, const int* in_sizes, int n_in,
                              void* d_out, int out_size, void* d_ws, size_t ws_size,
                              hipStream_t stream)
{
    // setup_inputs order: x, h_init, w_o, b_o, w_r, b_r, w_f, w_i
    const float* x  = (const float*)d_in[0];
    const float* h0 = (const float*)d_in[1];
    const float* wo = (const float*)d_in[2];
    const float* bo = (const float*)d_in[3];
    const float* wr = (const float*)d_in[4];
    const float* br = (const float*)d_in[5];
    const float* wf = (const float*)d_in[6];
    // d_in[7] (w_i) multiplies a zeros tensor in the reference — unused.

    uint4* ws = (uint4*)d_ws;
    float* out = (float*)d_out;

    const int total_pack = 32 * 512 + 32 * 256 + 32 * 512;  // 40960 uint4
    pack_weights<<<(total_pack + 255) / 256, 256, 0, stream>>>(wo, wr, wf, ws);
    tncn_scan<<<BATCH, 512, NST * 512 * 16, stream>>>(x, h0, bo, br, ws, out);
}

// Round 9
// 2775.086 us; speedup vs baseline: 5.4086x; 1.3166x over previous
//
#include <hip/hip_runtime.h>
#include <stdint.h>

// P_TNCN: seq=512, batch=128, states=512, out=256, inv_tau=0.5,
// alpha=0.01, beta=0.5.  float32 I/O.
//
// Per step (per batch row b, independent across b):
//   h_prior = 0.5*h + 0.5*(tanh(h) @ w_r^T + b_r)          [w_i term == 0]
//   x_pred  = tanh(h_prior) @ w_o^T + b_o
//   error   = x_pred - x_t                                   (output)
//   h_post  = h_prior - 0.01*sign(h_prior) - 0.5*(error @ w_f^T)
//
// R11: VALU-diet round.  R10 (fp8+perm-decode, 3654us) put VALU back on the
// critical path (active-CU VALUBusy ~54%): 1 v_perm per v_dot2.  This round
// keeps the same 584 KB/step L2 stream but switches w_r/w_o to per-matrix-
// scaled int8 consumed by v_dot4_i32_i8 (sdot4): 4 MACs/inst, zero decode.
// Activations (tanh outputs, exactly in (-1,1)) quantize to i8 at fixed
// scale 127; integer accumulation is exact; dequant = one mul per output.
// Numerics IMPROVE vs R10 (i8 ~1% RMS weight err vs e5m2 3.6%).  w_f stays
// f16 (sensitive O(1)-error path).  Pipeline: max-reduce kernel -> pack ->
// scan, all on-stream (capture-safe).  Structure else = R10 (128 blk x 512
// thr, NST=7 rows of A staged in 56 KB dyn LDS).  Workspace: 640 KB + 8 B.

#define SEQ   512
#define BATCH 128
#define SD    512
#define OD    256
#define NST   7     // A rows staged in LDS (7*512*16B = 57344 B)

typedef _Float16 h2_t __attribute__((ext_vector_type(2)));

#if __has_builtin(__builtin_amdgcn_fdot2)
#define HAS_FDOT2 1
#else
#define HAS_FDOT2 0
#endif
#if __has_builtin(__builtin_amdgcn_sdot4)
#define HAS_SDOT4 1
#else
#define HAS_SDOT4 0
#endif

__device__ __forceinline__ float tanh_fast(float x) {
    float e = __expf(2.0f * x);
    return 1.0f - 2.0f / (e + 1.0f);
}

__device__ __forceinline__ uint32_t pack_h2(float a, float b) {
    h2_t v;
    v.x = (_Float16)a;
    v.y = (_Float16)b;
    return __builtin_bit_cast(uint32_t, v);
}

__device__ __forceinline__ float dot2acc(uint32_t w, uint32_t a, float acc) {
#if HAS_FDOT2
    return __builtin_amdgcn_fdot2(__builtin_bit_cast(h2_t, a),
                                  __builtin_bit_cast(h2_t, w), acc, false);
#else
    h2_t av = __builtin_bit_cast(h2_t, a);
    h2_t wv = __builtin_bit_cast(h2_t, w);
    acc += (float)av.x * (float)wv.x;
    acc += (float)av.y * (float)wv.y;
    return acc;
#endif
}

// f16 path (phase C): uint4 = 8 f16 weights vs 8 f16 acts.
__device__ __forceinline__ float dot8(uint4 w, uint4 a, float acc) {
    acc = dot2acc(w.x, a.x, acc);
    acc = dot2acc(w.y, a.y, acc);
    acc = dot2acc(w.z, a.z, acc);
    acc = dot2acc(w.w, a.w, acc);
    return acc;
}

// i8 path: 4 signed-i8 MACs per instruction, i32 accumulate.
__device__ __forceinline__ int dot4i(uint32_t w, uint32_t a, int acc) {
#if HAS_SDOT4
    return __builtin_amdgcn_sdot4((int)w, (int)a, acc, false);
#else
    #pragma unroll
    for (int i = 0; i < 4; ++i)
        acc += (int)(signed char)((w >> (8 * i)) & 0xffu)
             * (int)(signed char)((a >> (8 * i)) & 0xffu);
    return acc;
#endif
}
// uint4 = 16 i8 weights vs 16 i8 acts.
__device__ __forceinline__ int dot16i(uint4 w, uint4 a, int acc) {
    acc = dot4i(w.x, a.x, acc);
    acc = dot4i(w.y, a.y, acc);
    acc = dot4i(w.z, a.z, acc);
    acc = dot4i(w.w, a.w, acc);
    return acc;
}

// ---------------------------------------------------------------------------
// Workspace layout (uint4 units):
//   A8i [32][512] : i8 w_r, A8i[k16][s] bytes = w_r[s][16k16..16k16+15] (256 KB)
//   O8i [32][256] : i8 w_o, O8i[k16][o] likewise                        (128 KB)
//   F4  [32][512] : f16 w_f, F4[o8][s] = w_f[s][8o8..8o8+7]             (256 KB)
//   scales: 2 floats at uint4-offset 40960: max|w_r|, max|w_o|.
// ---------------------------------------------------------------------------

__global__ void compute_scales(const float* __restrict__ w_r,
                               const float* __restrict__ w_o,
                               float* __restrict__ sc)
{
    __shared__ float red[1024];
    const float* src = (blockIdx.x == 0) ? w_r : w_o;
    const int n = (blockIdx.x == 0) ? (512 * 512) : (256 * 512);
    float m = 0.0f;
    for (int i = threadIdx.x; i < n; i += 1024) m = fmaxf(m, fabsf(src[i]));
    red[threadIdx.x] = m;
    __syncthreads();
    for (int off = 512; off > 0; off >>= 1) {
        if (threadIdx.x < off)
            red[threadIdx.x] = fmaxf(red[threadIdx.x], red[threadIdx.x + off]);
        __syncthreads();
    }
    if (threadIdx.x == 0) sc[blockIdx.x] = fmaxf(red[0], 1e-20f);
}

__global__ void pack_weights(const float* __restrict__ w_o,
                             const float* __restrict__ w_r,
                             const float* __restrict__ w_f,
                             uint4* __restrict__ ws)
{
    const int nA = 32 * 512;   // 16384 uint4
    const int nO = 32 * 256;   //  8192
    const int nF = 32 * 512;   // 16384
    const float* sc = (const float*)(ws + nA + nO + nF);
    int i = blockIdx.x * 256 + threadIdx.x;
    if (i < nA + nO) {
        const float* p;
        float qs;
        if (i < nA) {
            int k16 = i >> 9, s = i & 511;
            p  = &w_r[s * 512 + 16 * k16];
            qs = 127.0f / sc[0];
        } else {
            int j = i - nA;
            int k16 = j >> 8, o = j & 255;
            p  = &w_o[o * 512 + 16 * k16];
            qs = 127.0f / sc[1];
        }
        uint32_t q[4];
        #pragma unroll
        for (int g = 0; g < 4; ++g) {
            uint32_t v = 0;
            #pragma unroll
            for (int j = 0; j < 4; ++j) {
                int qi = (int)rintf(p[4 * g + j] * qs);
                v |= ((uint32_t)qi & 0xffu) << (8 * j);
            }
            q[g] = v;
        }
        ws[i] = make_uint4(q[0], q[1], q[2], q[3]);
    } else if (i < nA + nO + nF) {
        int j = i - nA - nO;
        int o8 = j >> 9, s = j & 511;
        const float* p = &w_f[s * 256 + 8 * o8];
        ws[i] = make_uint4(pack_h2(p[0], p[1]), pack_h2(p[2], p[3]),
                           pack_h2(p[4], p[5]), pack_h2(p[6], p[7]));
    }
}

// ---------------------------------------------------------------------------
// Main sequential scan: one block per batch row, h state in registers (s=tid).
// A8i rows [0,NST) live in LDS (loaded once); ascending-k accumulation.
// ---------------------------------------------------------------------------
__global__ __launch_bounds__(512)
void tncn_scan(const float* __restrict__ x,       // [512][128][256]
               const float* __restrict__ h_init,  // [128][512]
               const float* __restrict__ b_o,     // [256]
               const float* __restrict__ b_r,     // [512]
               const uint4* __restrict__ wsv,
               float* __restrict__ out)           // [512][128][256]
{
    const uint4* A8i = wsv;                       // [32][512]
    const uint4* O8i = wsv + 32 * 512;            // [32][256]
    const uint4* F4  = wsv + 32 * 512 + 32 * 256; // [32][512]
    const float* scv = (const float*)(wsv + 32 * 512 + 32 * 256 + 32 * 512);

    extern __shared__ __align__(16) char smem_raw[];
    uint4* sA = (uint4*)smem_raw;                 // [NST*512] staged A8i rows

    __shared__ __align__(16) signed char thA8[512];  // i8 tanh(h_post)
    __shared__ __align__(16) signed char thB8[512];  // i8 tanh(h_prior)
    __shared__ __align__(16) _Float16 erh[256];      // f16 error vector
    __shared__ float part[512];                      // x_pred partial sums

    const int b   = blockIdx.x;
    const int tid = threadIdx.x;
    const int o   = tid & 255;
    const int kh  = tid >> 8;    // 0/1: k-half for phase B

    const float brf = b_r[tid];
    const float bof = (tid < 256) ? b_o[tid] : 0.0f;
    // Dequant factors: weight q*(max/127) times act q*(1/127).
    const float fA = scv[0] * (1.0f / 16129.0f);
    const float fO = scv[1] * (1.0f / 16129.0f);

    // Stage A8i rows [0, NST) into LDS once (coalesced).
    #pragma unroll
    for (int r = 0; r < NST; ++r)
        sA[r * 512 + tid] = A8i[r * 512 + tid];

    float hpost = h_init[b * SD + tid];
    thA8[tid] = (signed char)__float2int_rn(tanh_fast(hpost) * 127.0f);
    __syncthreads();

    const uint4* actA = (const uint4*)thA8;   // [32] x 16 acts
    const uint4* actB = (const uint4*)thB8;

    for (int t = 0; t < SEQ; ++t) {
        // Hoisted x_t load (consumed one matvec later; latency hidden).
        float xv = 0.0f;
        if (tid < 256) xv = x[(t * BATCH + b) * OD + tid];

        // ---- Phase A: h_prior[s=tid] = 0.5*h + 0.5*(tanh(h)@w_r^T + b_r)
        int acci = 0;
        #pragma unroll
        for (int k16 = 0; k16 < NST; ++k16)            // LDS-staged rows
            acci = dot16i(sA[(k16 << 9) + tid], actA[k16], acci);
        #pragma unroll 5
        for (int k16 = NST; k16 < 32; ++k16)           // L2 stream
            acci = dot16i(A8i[(k16 << 9) + tid], actA[k16], acci);
        float hp = 0.5f * hpost + 0.5f * ((float)acci * fA + brf);
        thB8[tid] = (signed char)__float2int_rn(tanh_fast(hp) * 127.0f);
        __syncthreads();

        // ---- Phase B: x_pred[o] = tanh(h_prior)@w_o^T + b_o ; err = xp - x
        int accBi = 0;
        {
            const int k160 = kh * 16;
            #pragma unroll 8
            for (int k16i = 0; k16i < 16; ++k16i) {
                const int k16 = k160 + k16i;
                accBi = dot16i(O8i[(k16 << 8) + o], actB[k16], accBi);
            }
        }
        part[tid] = (float)accBi * fO;
        __syncthreads();
        if (tid < 256) {
            float xp = part[tid] + part[tid + 256] + bof;
            float e  = xp - xv;
            erh[tid] = (_Float16)e;
            out[(t * BATCH + b) * OD + tid] = e;
        }
        __syncthreads();

        // ---- Phase C: h_post[s] = h_prior - 0.01*sign(h_prior) - 0.5*(er@w_f^T)
        float accC = 0.0f;
        #pragma unroll 8
        for (int o8 = 0; o8 < 32; ++o8) {
            uint4 u = F4[(o8 << 9) + tid];
            uint4 e = *(const uint4*)&erh[8 * o8];
            accC = dot8(u, e, accC);
        }
        float sg = (hp > 0.0f) ? 1.0f : ((hp < 0.0f) ? -1.0f : 0.0f);
        hpost = hp - 0.01f * sg - 0.5f * accC;
        thA8[tid] = (signed char)__float2int_rn(tanh_fast(hpost) * 127.0f);
        __syncthreads();
    }
}

extern "C" void kernel_launch(void* const* d_in, const int* in_sizes, int n_in,
                              void* d_out, int out_size, void* d_ws, size_t ws_size,
                              hipStream_t stream)
{
    // setup_inputs order: x, h_init, w_o, b_o, w_r, b_r, w_f, w_i
    const float* x  = (const float*)d_in[0];
    const float* h0 = (const float*)d_in[1];
    const float* wo = (const float*)d_in[2];
    const float* bo = (const float*)d_in[3];
    const float* wr = (const float*)d_in[4];
    const float* br = (const float*)d_in[5];
    const float* wf = (const float*)d_in[6];
    // d_in[7] (w_i) multiplies a zeros tensor in the reference — unused.

    uint4* ws  = (uint4*)d_ws;
    float* out = (float*)d_out;

    const int total_img = 32 * 512 + 32 * 256 + 32 * 512;  // 40960 uint4
    float* sc = (float*)(ws + total_img);

    compute_scales<<<2, 1024, 0, stream>>>(wr, wo, sc);
    pack_weights<<<(total_img + 255) / 256, 256, 0, stream>>>(wo, wr, wf, ws);
    tncn_scan<<<BATCH, 512, NST * 512 * 16, stream>>>(x, h0, bo, br, ws, out);
}